// Round 1
// baseline (282.635 us; speedup 1.0000x reference)
//
#include <hip/hip_runtime.h>
#include <hip/hip_bf16.h>
#include <math.h>

#define Bb 2
#define Ss 2048
#define Ee 1024
#define Hh 16
#define HDd 64
#define NEG_INF_F -1000000000.0f

typedef __attribute__((ext_vector_type(8))) short bfrag;     // 8 bf16
typedef __attribute__((ext_vector_type(4))) float ffrag;     // 16x16 C/D
typedef __attribute__((ext_vector_type(16))) float ffrag16;  // 32x32 C/D
typedef __attribute__((ext_vector_type(8))) unsigned short us8;

#define C1F 0.1803368801f  /* 0.125 * log2(e) — folded into Q at gemm_qkv */

// ---- bf16 helpers ----------------------------------------------------------
__device__ __forceinline__ unsigned short f2bf(float x) {
  unsigned u = __float_as_uint(x);
  u += 0x7fffu + ((u >> 16) & 1u);
  return (unsigned short)(u >> 16);
}
__device__ __forceinline__ float bf2f(unsigned short h) {
  return __uint_as_float(((unsigned)h) << 16);
}

__device__ __forceinline__ void async_copy16(void* lds, const void* g) {
  __builtin_amdgcn_global_load_lds(
      (const __attribute__((address_space(1))) unsigned int*)g,
      (__attribute__((address_space(3))) unsigned int*)lds, 16, 0, 0);
}

// ---------------------------------------------------------------------------
// Fused split pass: x (4M) -> hi only; Wqkv (3M), Wout (1M) -> hi/lo.
// ---------------------------------------------------------------------------
__global__ __launch_bounds__(256) void split_all(
    const float* __restrict__ x, unsigned short* __restrict__ xh,
    const float* __restrict__ wq, unsigned short* __restrict__ wqh,
    unsigned short* __restrict__ wql,
    const float* __restrict__ wo, unsigned short* __restrict__ woh,
    unsigned short* __restrict__ wol) {
  int bid = blockIdx.x;
  const float* in;
  unsigned short *hi, *lo;
  if (bid < 4096) { in = x; hi = xh; lo = nullptr; }
  else if (bid < 7168) { bid -= 4096; in = wq; hi = wqh; lo = wql; }
  else { bid -= 7168; in = wo; hi = woh; lo = wol; }
  const int idx = (bid * 256 + threadIdx.x) * 4;
  const float4 v = *(const float4*)(in + idx);
  unsigned short h0 = f2bf(v.x), h1 = f2bf(v.y), h2 = f2bf(v.z), h3 = f2bf(v.w);
  ushort4 hv = {h0, h1, h2, h3};
  *(ushort4*)(hi + idx) = hv;
  if (lo) {
    ushort4 lv = {f2bf(v.x - bf2f(h0)), f2bf(v.y - bf2f(h1)),
                  f2bf(v.z - bf2f(h2)), f2bf(v.w - bf2f(h3))};
    *(ushort4*)(lo + idx) = lv;
  }
}

// ---------------------------------------------------------------------------
// LDS slot map (rows of 32 bf16 = 4 x 16B chunks):
// slot(row,q) = (row>>1)*8 + ((((row&1)*4)|q) ^ ((row>>1)&7)).
// ---------------------------------------------------------------------------
__device__ __forceinline__ int gemm_slot(int row, int q) {
  return (row >> 1) * 8 + ((((row & 1) * 4) | q) ^ ((row >> 1) & 7));
}
__device__ __forceinline__ int slot_src_off(int slot, int ld) {
  const int dr = slot >> 3;
  const int idx8 = (slot & 7) ^ (dr & 7);
  const int row = dr * 2 + (idx8 >> 2);
  const int q = idx8 & 3;
  return row * ld + q * 8;
}

// ---------------------------------------------------------------------------
// QKV GEMM, 32x32x16 core: C = xh * (Wh + Wl)^T + bias (2 MFMAs/product).
// 128x128 tile. Epilogue (all single bf16): Q pre-scaled by C1F -> [bh][s][64];
// K -> [bh][s][64]; V^T -> [bh][d][s].
// ---------------------------------------------------------------------------
__global__ __launch_bounds__(256) void gemm_qkv(
    const unsigned short* __restrict__ Ah,
    const unsigned short* __restrict__ Bh, const unsigned short* __restrict__ Bl,
    const float* __restrict__ bias,
    unsigned short* __restrict__ q_h, unsigned short* __restrict__ k_h,
    unsigned short* __restrict__ vt_h) {
  __shared__ unsigned short sm[3 * 4096];
  const int tid = threadIdx.x;
  const int lane = tid & 63;
  const int w = tid >> 6;
  const int wm = w >> 1;
  const int wn = w & 1;
  const int l31 = lane & 31;
  const int e = lane >> 5;
  const int m0 = blockIdx.x * 128;
  const int n0 = blockIdx.y * 128;

  int coff[2], ldsb[2];
#pragma unroll
  for (int u = 0; u < 2; ++u) {
    const int slot = w * 128 + u * 64 + lane;
    coff[u] = slot_src_off(slot, 1024);
    ldsb[u] = (w * 128 + u * 64) * 8;
  }
  const unsigned short* srcs[3] = {
      Ah + (size_t)m0 * 1024, Bh + (size_t)n0 * 1024, Bl + (size_t)n0 * 1024};

  ffrag16 acc[2][2];
#pragma unroll
  for (int i = 0; i < 2; ++i)
#pragma unroll
    for (int j = 0; j < 2; ++j) acc[i][j] = (ffrag16)0.f;

  int ca[2][2], cb[2][2];
#pragma unroll
  for (int t = 0; t < 2; ++t)
#pragma unroll
    for (int h2 = 0; h2 < 2; ++h2) {
      ca[t][h2] = gemm_slot(wm * 64 + t * 32 + l31, h2 * 2 + e) * 8;
      cb[t][h2] = gemm_slot(wn * 64 + t * 32 + l31, h2 * 2 + e) * 8;
    }

  for (int k0 = 0; k0 < 1024; k0 += 32) {
    __syncthreads();
#pragma unroll
    for (int t = 0; t < 3; ++t)
#pragma unroll
      for (int u = 0; u < 2; ++u)
        async_copy16(&sm[t * 4096 + ldsb[u]], srcs[t] + coff[u] + k0);
    __syncthreads();

    bfrag ah[2][2], bhf[2][2], blf[2][2];
#pragma unroll
    for (int t = 0; t < 2; ++t)
#pragma unroll
      for (int h2 = 0; h2 < 2; ++h2) {
        ah[t][h2] = *(const bfrag*)&sm[0 * 4096 + ca[t][h2]];
        bhf[t][h2] = *(const bfrag*)&sm[1 * 4096 + cb[t][h2]];
        blf[t][h2] = *(const bfrag*)&sm[2 * 4096 + cb[t][h2]];
      }
#pragma unroll
    for (int mt = 0; mt < 2; ++mt)
#pragma unroll
      for (int nt = 0; nt < 2; ++nt)
#pragma unroll
        for (int h2 = 0; h2 < 2; ++h2) {
          acc[mt][nt] = __builtin_amdgcn_mfma_f32_32x32x16_bf16(
              ah[mt][h2], bhf[nt][h2], acc[mt][nt], 0, 0, 0);
          acc[mt][nt] = __builtin_amdgcn_mfma_f32_32x32x16_bf16(
              ah[mt][h2], blf[nt][h2], acc[mt][nt], 0, 0, 0);
        }
  }

#pragma unroll
  for (int nt = 0; nt < 2; ++nt) {
    const int n = n0 + wn * 64 + nt * 32 + l31;
    const float bv = bias[n];
    const int h = n / 192;
    const int c = n - h * 192;
    const int d = c & 63;
#pragma unroll
    for (int mt = 0; mt < 2; ++mt) {
      if (c >= 128) {
#pragma unroll
        for (int g = 0; g < 4; ++g) {
          const int m = m0 + wm * 64 + mt * 32 + g * 8 + e * 4;
          const int bidx = m >> 11;
          const int s = m & 2047;
          ushort4 hv4;
          unsigned short* ph = (unsigned short*)&hv4;
#pragma unroll
          for (int r = 0; r < 4; ++r)
            ph[r] = f2bf(acc[mt][nt][g * 4 + r] + bv);
          const size_t off =
              (size_t)(bidx * 16 + h) * (64 * 2048) + (size_t)d * 2048 + s;
          *(ushort4*)(vt_h + off) = hv4;
        }
      } else {
        const float scale = (c < 64) ? C1F : 1.0f;
        unsigned short* dh = (c < 64) ? q_h : k_h;
#pragma unroll
        for (int g = 0; g < 4; ++g)
#pragma unroll
          for (int r = 0; r < 4; ++r) {
            const int m = m0 + wm * 64 + mt * 32 + g * 8 + e * 4 + r;
            const int bidx = m >> 11;
            const int s = m & 2047;
            const size_t off =
                (size_t)(bidx * 16 + h) * (2048 * 64) + (size_t)s * 64 + d;
            dh[off] = f2bf((acc[mt][nt][g * 4 + r] + bv) * scale);
          }
      }
    }
  }
}

// ---------------------------------------------------------------------------
// Out-proj GEMM: A = vals single bf16, B = Wout hi/lo (2 MFMAs/product).
// 128x64 tile, 512 blocks. Writes fp32+bias directly to out.
// ---------------------------------------------------------------------------
__global__ __launch_bounds__(256) void gemm_out2(
    const unsigned short* __restrict__ A,
    const unsigned short* __restrict__ Bh, const unsigned short* __restrict__ Bl,
    const float* __restrict__ bias, float* __restrict__ out) {
  __shared__ unsigned short sm[8192];
  const int tid = threadIdx.x;
  const int lane = tid & 63;
  const int w = tid >> 6;
  const int wm = w >> 1;
  const int wn = w & 1;
  const int l31 = lane & 31;
  const int e = lane >> 5;
  const int m0 = blockIdx.x * 128;
  const int n0 = blockIdx.y * 64;

  int acoff[2], aldsb[2];
#pragma unroll
  for (int u = 0; u < 2; ++u) {
    const int slot = w * 128 + u * 64 + lane;
    acoff[u] = slot_src_off(slot, 1024);
    aldsb[u] = (w * 128 + u * 64) * 8;
  }
  const int bslot = w * 64 + lane;
  const int bcoff = slot_src_off(bslot, 1024);
  const int bldsb = bslot * 8;

  const unsigned short* Ap  = A + (size_t)m0 * 1024;
  const unsigned short* Bph = Bh + (size_t)n0 * 1024;
  const unsigned short* Bpl = Bl + (size_t)n0 * 1024;

  ffrag16 acc[2];
  acc[0] = (ffrag16)0.f;
  acc[1] = (ffrag16)0.f;

  int ca[2][2], cb[2];
#pragma unroll
  for (int t = 0; t < 2; ++t)
#pragma unroll
    for (int h2 = 0; h2 < 2; ++h2)
      ca[t][h2] = gemm_slot(wm * 64 + t * 32 + l31, h2 * 2 + e) * 8;
#pragma unroll
  for (int h2 = 0; h2 < 2; ++h2)
    cb[h2] = gemm_slot(wn * 32 + l31, h2 * 2 + e) * 8;

  for (int k0 = 0; k0 < 1024; k0 += 32) {
    __syncthreads();
#pragma unroll
    for (int u = 0; u < 2; ++u)
      async_copy16(&sm[0 + aldsb[u]], Ap + acoff[u] + k0);
    async_copy16(&sm[4096 + bldsb], Bph + bcoff + k0);
    async_copy16(&sm[6144 + bldsb], Bpl + bcoff + k0);
    __syncthreads();

    bfrag ah[2][2], bhf[2], blf[2];
#pragma unroll
    for (int t = 0; t < 2; ++t)
#pragma unroll
      for (int h2 = 0; h2 < 2; ++h2)
        ah[t][h2] = *(const bfrag*)&sm[0 + ca[t][h2]];
#pragma unroll
    for (int h2 = 0; h2 < 2; ++h2) {
      bhf[h2] = *(const bfrag*)&sm[4096 + cb[h2]];
      blf[h2] = *(const bfrag*)&sm[6144 + cb[h2]];
    }
#pragma unroll
    for (int mt = 0; mt < 2; ++mt)
#pragma unroll
      for (int h2 = 0; h2 < 2; ++h2) {
        acc[mt] = __builtin_amdgcn_mfma_f32_32x32x16_bf16(
            ah[mt][h2], bhf[h2], acc[mt], 0, 0, 0);
        acc[mt] = __builtin_amdgcn_mfma_f32_32x32x16_bf16(
            ah[mt][h2], blf[h2], acc[mt], 0, 0, 0);
      }
  }

  const int n = n0 + wn * 32 + l31;
  const float bv = bias[n];
#pragma unroll
  for (int mt = 0; mt < 2; ++mt)
#pragma unroll
    for (int g = 0; g < 4; ++g)
#pragma unroll
      for (int r = 0; r < 4; ++r) {
        const int m = m0 + wm * 64 + mt * 32 + g * 8 + e * 4 + r;
        out[(size_t)m * 1024 + n] = acc[mt][g * 4 + r] + bv;
      }
}

// ---------------------------------------------------------------------------
// Wave-scheduled flash attention — NO LDS staging, NO barriers.
// Theory: attn_pair was latency-bound (MFMA pipe ~3% busy, HBM 1.4%): only
// 2 waves/SIMD, and a vmcnt+s_barrier every iteration lock-stepped the block
// around the staging DMA. But K [bh][s][64] and V^T [bh][d][s] are laid out so
// every MFMA B-fragment is a contiguous 16B global load — and K/V tiles are
// L1/L2-resident (512KB/head, shared by waves reading the same kt). So:
//   - load K/V fragments straight from global (no LDS staging, no DMA);
//   - only LDS use left is the wave-LOCAL P transpose -> zero barriers;
//   - un-pair mt0/mt1 into separate waves: 8 waves/block, waves 0-3 own rows
//     64y+16wi (kt = y..31), waves 4-7 own rows 64(31-y)+16wi (kt = 31-y..31,
//     they simply start later — legal with no barriers). Per-block wave-iters
//     = 4(32-y)+4(y+1) = 132 for every y -> balanced CUs.
// LDS 16KB (P only); __launch_bounds__(512,4) pins 4 waves/SIMD -> 16
// waves/CU (2x the old kernel).
// Row 2047 (fully masked -> uniform) = mean(V): computed by the (y=0,w=3)
// wave which sees all 32 V tiles (Vsum ones-MFMA); the (y=0,w=7) wave skips
// its s==2047 store. Per-row arithmetic identical to the previous version.
// ---------------------------------------------------------------------------
__global__ __launch_bounds__(512, 4) void attn_ws(
    const unsigned short* __restrict__ qh, const unsigned short* __restrict__ kh,
    const unsigned short* __restrict__ vth, unsigned short* __restrict__ vals) {
  __shared__ unsigned short smP[8 * 16 * 64];  // 16KB: per-wave 16x64 P slice
  const int tid = threadIdx.x;
  const int lane = tid & 63;
  const int w = tid >> 6;        // 0..7
  const int wi = w & 3;
  const bool isB = (w >= 4);
  const int l15 = lane & 15;
  const int quad = lane >> 4;
  const int bh = blockIdx.x;
  const int y = blockIdx.y;      // 0..15
  const int yb = isB ? (31 - y) : y;
  const int rb = 64 * yb + 16 * wi;   // this wave's 16 query rows
  const int kt0 = yb;                 // first unmasked key tile
  const size_t base = (size_t)bh * (Ss * HDd);
  const bool fixsrc = (y == 0) && (w == 3);   // sees all kt; owns the fix
  const bool fixskip = (y == 0) && (w == 7);  // nominal owner of row 2047

  // Q fragments (Q pre-scaled by 0.125*log2e at gemm_qkv)
  bfrag Qf[2];
#pragma unroll
  for (int ks = 0; ks < 2; ++ks)
    Qf[ks] = *(const bfrag*)(qh + base + (size_t)(rb + l15) * 64 + ks * 32 + quad * 8);

  bfrag vone;
#pragma unroll
  for (int j = 0; j < 8; ++j) vone[j] = (short)0x3F80;  // bf16 1.0

  ffrag O[4], Oe, Vsum[4];
#pragma unroll
  for (int dt = 0; dt < 4; ++dt) { O[dt] = (ffrag)0.f; Vsum[dt] = (ffrag)0.f; }
  Oe = (ffrag)0.f;

  const int pbase = w * (16 * 64);  // wave-local P slice (shorts)

  for (int kt = kt0; kt < 32; ++kt) {
    const bool partial = (kt == kt0);

    // ---- S = Q K^T (K fragments straight from global; contiguous 16B each)
    ffrag S[4];
#pragma unroll
    for (int nt = 0; nt < 4; ++nt) S[nt] = (ffrag)0.f;
#pragma unroll
    for (int nt = 0; nt < 4; ++nt) {
      const int krow = kt * 64 + nt * 16 + l15;
#pragma unroll
      for (int ks = 0; ks < 2; ++ks) {
        const bfrag kbh =
            *(const bfrag*)(kh + base + (size_t)krow * 64 + ks * 32 + quad * 8);
        S[nt] = __builtin_amdgcn_mfma_f32_16x16x32_bf16(Qf[ks], kbh, S[nt], 0, 0, 0);
      }
    }

    // ---- p = exp2(S [+ CM if masked]); packed bf16 cvt; store to P LDS
    const float CM = -1.442695041e9f;  // -1e9 * log2(e)
#pragma unroll
    for (int nt = 0; nt < 4; ++nt) {
      const int key = nt * 16 + l15;
#pragma unroll
      for (int rp = 0; rp < 2; ++rp) {
        float t0 = S[nt][2 * rp];
        float t1 = S[nt][2 * rp + 1];
        if (partial) {
          const int jg = kt * 64 + key;
          const int ig = rb + quad * 4 + 2 * rp;
          if (jg <= ig) t0 += CM;
          if (jg <= ig + 1) t1 += CM;
        }
        float2 pf;
        pf.x = __builtin_amdgcn_exp2f(t0);
        pf.y = __builtin_amdgcn_exp2f(t1);
        const __hip_bfloat162 pb = __float22bfloat162_rn(pf);
        const unsigned short* pbs = (const unsigned short*)&pb;
        const int pr0 = quad * 4 + 2 * rp;
        smP[pbase + pr0 * 64 + (((key >> 3) ^ (pr0 & 7)) * 8 + (key & 7))] = pbs[0];
        const int pr1 = pr0 + 1;
        smP[pbase + pr1 * 64 + (((key >> 3) ^ (pr1 & 7)) * 8 + (key & 7))] = pbs[1];
      }
    }

    // ---- PV (V fragments straight from global) + l via ones-MFMA
#pragma unroll
    for (int ks = 0; ks < 2; ++ks) {
      const bfrag pA =
          *(const bfrag*)&smP[pbase + l15 * 64 + (((ks * 4 + quad) ^ (l15 & 7)) * 8)];
      Oe = __builtin_amdgcn_mfma_f32_16x16x32_bf16(pA, vone, Oe, 0, 0, 0);
#pragma unroll
      for (int dt = 0; dt < 4; ++dt) {
        const bfrag vbh = *(const bfrag*)(vth + base + (size_t)(dt * 16 + l15) * 2048 +
                                          kt * 64 + ks * 32 + quad * 8);
        O[dt] = __builtin_amdgcn_mfma_f32_16x16x32_bf16(pA, vbh, O[dt], 0, 0, 0);
        if (fixsrc)
          Vsum[dt] = __builtin_amdgcn_mfma_f32_16x16x32_bf16(vone, vbh, Vsum[dt], 0, 0, 0);
      }
    }
  }

  // ---- epilogue: vals[b][s][h*64+d] single bf16; l = Oe row sum.
  const int b = bh >> 4;
  const int h = bh & 15;
#pragma unroll
  for (int r = 0; r < 4; ++r) {
    const float inv = 1.0f / Oe[r];
    const int s = rb + quad * 4 + r;
    const size_t rowoff = ((size_t)b * 2048 + s) * 1024 + h * 64;
#pragma unroll
    for (int dt = 0; dt < 4; ++dt) {
      if (fixskip && s == 2047) continue;  // row 2047 written by fixsrc wave
      vals[rowoff + dt * 16 + l15] = f2bf(O[dt][r] * inv);
    }
  }
  if (fixsrc && quad == 3) {  // row 2047 = mean(V); 16 lanes cover d per dt
    const size_t rowoff = ((size_t)b * 2048 + 2047) * 1024 + h * 64;
#pragma unroll
    for (int dt = 0; dt < 4; ++dt)
      vals[rowoff + dt * 16 + l15] = f2bf(Vsum[dt][3] * (1.0f / 2048.0f));
  }
}

// ---------------------------------------------------------------------------
// ws (64 MB): qh[0,8) kh[8,16) vth[16,24) vals[24,32)
// wqh[48,54) wql[54,60) woh[60,62) wol[62,64).
// d_out: xh[0,8) (dead after gemm_qkv); gemm_out2 writes final fp32 directly.
// ---------------------------------------------------------------------------
extern "C" void kernel_launch(void* const* d_in, const int* in_sizes, int n_in,
                              void* d_out, int out_size, void* d_ws, size_t ws_size,
                              hipStream_t stream) {
  const float* x    = (const float*)d_in[0];
  const float* Wqkv = (const float*)d_in[1];
  const float* bqkv = (const float*)d_in[2];
  const float* Wout = (const float*)d_in[3];
  const float* bout = (const float*)d_in[4];
  float* out = (float*)d_out;
  char* wsb = (char*)d_ws;

  unsigned short* qhp  = (unsigned short*)d_ws;
  unsigned short* khp  = qhp + 1 * 4194304;
  unsigned short* vthp = qhp + 2 * 4194304;
  unsigned short* vals = qhp + 3 * 4194304;
  unsigned short* wqh  = (unsigned short*)(wsb + (48u << 20));
  unsigned short* wql  = (unsigned short*)(wsb + (54u << 20));
  unsigned short* woh  = (unsigned short*)(wsb + (60u << 20));
  unsigned short* wol  = (unsigned short*)(wsb + (62u << 20));
  unsigned short* xh   = (unsigned short*)d_out;

  dim3 blk(256);
  split_all<<<8192, blk, 0, stream>>>(x, xh, Wqkv, wqh, wql, Wout, woh, wol);
  gemm_qkv<<<dim3(32, 24), blk, 0, stream>>>(xh, wqh, wql, bqkv, qhp, khp, vthp);
  attn_ws<<<dim3(32, 16), dim3(512), 0, stream>>>(qhp, khp, vthp, vals);
  gemm_out2<<<dim3(32, 16), blk, 0, stream>>>(vals, woh, wol, bout, out);
}